// Round 4
// baseline (313.653 us; speedup 1.0000x reference)
//
#include <hip/hip_runtime.h>

#define D  128
#define NF 3
#define V  8

typedef __attribute__((ext_vector_type(8))) short short8;
typedef __attribute__((ext_vector_type(4))) float f32x4;

__device__ inline unsigned short f2bf(float x) {
    unsigned u = __builtin_bit_cast(unsigned, x);
    return (unsigned short)((u + 0x7FFFu + ((u >> 16) & 1u)) >> 16);   // RNE
}

// ---------------- build stage ----------------

__global__ __launch_bounds__(256) void hist_kernel(
    const int* __restrict__ dst, int* __restrict__ count, int E)
{
    int t = blockIdx.x * 256 + threadIdx.x;
    if (t < E) atomicAdd(&count[dst[t]], 1);
}

// Mixed-role dispatch: block 0 = exclusive scan of count[] (offset+cursor);
// blocks 1..64 = combined edge-embedding table T[512][128] (fp32);
// blocks 65..80 = W -> B-fragment-order bf16 table WB[16384].
__global__ __launch_bounds__(1024) void prep_kernel(
    const int* __restrict__ count, int* __restrict__ offset, int* __restrict__ cursor,
    const float* __restrict__ emb, float* __restrict__ T,
    const float* __restrict__ Wm, unsigned short* __restrict__ WB, int N)
{
    int b = blockIdx.x;
    if (b == 0) {
        int tid = threadIdx.x;
        int chunk = (N + 1023) >> 10;
        int start = tid * chunk;
        int end = min(start + chunk, N);
        int s = 0;
        for (int i = start; i < end; ++i) s += count[i];
        int lane = tid & 63, wv = tid >> 6;
        int inc = s;
        for (int d = 1; d < 64; d <<= 1) {
            int u = __shfl_up(inc, d);
            if (lane >= d) inc += u;
        }
        __shared__ int wsum[16];
        if (lane == 63) wsum[wv] = inc;
        __syncthreads();
        int base = 0;
        for (int w = 0; w < wv; ++w) base += wsum[w];
        int run = base + inc - s;
        for (int i = start; i < end; ++i) {
            offset[i] = run;
            cursor[i] = run;
            run += count[i];
        }
    } else if (b <= 64) {
        int tid = (b - 1) * 1024 + threadIdx.x;   // 0..65535
        int cmb = tid >> 7, c = tid & 127;
        T[tid] = emb[(cmb & 7) * D + c]
               + emb[(V + ((cmb >> 3) & 7)) * D + c]
               + emb[(2 * V + (cmb >> 6)) * D + c];
    } else {
        // WB[((n*4+ks)*64 + lane)*8 + j] = bf16(W[ks*32 + (lane>>4)*8 + j][n*16 + (lane&15)])
        int tid = (b - 65) * 1024 + threadIdx.x;  // 0..16383
        int j = tid & 7, lane = (tid >> 3) & 63, ks = (tid >> 9) & 3, n = tid >> 11;
        int k = ks * 32 + ((lane >> 4) << 3) + j;
        int c = n * 16 + (lane & 15);
        WB[tid] = f2bf(Wm[k * D + c]);
    }
}

// scatter packed (src | combined_emb_idx<<16) records into dst-sorted order
__global__ __launch_bounds__(256) void scatter_kernel(
    const int* __restrict__ src, const int* __restrict__ dst,
    const int* __restrict__ eidx, int* __restrict__ cursor,
    unsigned* __restrict__ packed, int E)
{
    int t = blockIdx.x * 256 + threadIdx.x;
    if (t < E) {
        int i0 = eidx[t * NF + 0];
        int i1 = eidx[t * NF + 1];
        int i2 = eidx[t * NF + 2];
        unsigned ci = (unsigned)(i0 + (i1 << 3) + (i2 << 6));
        int pos = atomicAdd(&cursor[dst[t]], 1);
        packed[pos] = (unsigned)src[t] | (ci << 16);
    }
}

// ---------------- gather: one wave per node, writes bf16 h row ----------------

__global__ __launch_bounds__(256) void gather_kernel(
    const float* __restrict__ nfeat,
    const unsigned* __restrict__ packed,
    const int* __restrict__ offset,
    const int* __restrict__ count,
    const float* __restrict__ T,
    unsigned short* __restrict__ hbuf,
    int N)
{
    int wid = (blockIdx.x * 256 + threadIdx.x) >> 6;
    int lane = threadIdx.x & 63;
    if (wid >= N) return;

    const float2* nf2 = (const float2*)nfeat;
    const float2* T2  = (const float2*)T;

    int off = offset[wid];
    int cnt = count[wid];
    float2 acc = nf2[wid * 64 + lane];

    for (int base = 0; base < cnt; base += 64) {
        int m = min(64, cnt - base);
        unsigned rec = (lane < m) ? packed[off + base + lane] : 0u;
        int j = 0;
        for (; j + 4 <= m; j += 4) {
            unsigned u0 = __shfl((int)rec, j);
            unsigned u1 = __shfl((int)rec, j + 1);
            unsigned u2 = __shfl((int)rec, j + 2);
            unsigned u3 = __shfl((int)rec, j + 3);
            float2 a0 = nf2[(u0 & 0xFFFFu) * 64 + lane];
            float2 t0 = T2[(u0 >> 16) * 64 + lane];
            float2 a1 = nf2[(u1 & 0xFFFFu) * 64 + lane];
            float2 t1 = T2[(u1 >> 16) * 64 + lane];
            float2 a2 = nf2[(u2 & 0xFFFFu) * 64 + lane];
            float2 t2 = T2[(u2 >> 16) * 64 + lane];
            float2 a3 = nf2[(u3 & 0xFFFFu) * 64 + lane];
            float2 t3 = T2[(u3 >> 16) * 64 + lane];
            acc.x += (a0.x + t0.x) + (a1.x + t1.x) + (a2.x + t2.x) + (a3.x + t3.x);
            acc.y += (a0.y + t0.y) + (a1.y + t1.y) + (a2.y + t2.y) + (a3.y + t3.y);
        }
        for (; j < m; ++j) {
            unsigned u = __shfl((int)rec, j);
            float2 a = nf2[(u & 0xFFFFu) * 64 + lane];
            float2 t = T2[(u >> 16) * 64 + lane];
            acc.x += a.x + t.x;
            acc.y += a.y + t.y;
        }
    }

    float inv = 1.0f / (float)(cnt + 1);
    acc.x *= inv; acc.y *= inv;
    unsigned hx = (unsigned)f2bf(acc.x) | ((unsigned)f2bf(acc.y) << 16);
    ((unsigned*)hbuf)[wid * 64 + lane] = hx;
}

// ---------------- projection via MFMA: out = h @ W + b ----------------
// 64 rows/block, 4 waves; wave w computes rows [w*16, w*16+16) x all 128 cols.
// mfma_f32_16x16x32_bf16: A[m=lane&15][k=(lane>>4)*8+j], B[k][n=lane&15],
// C/D: col=lane&15, row=(lane>>4)*4+reg.

__global__ __launch_bounds__(256) void proj_kernel(
    const unsigned short* __restrict__ hbuf,
    const unsigned short* __restrict__ WB,
    const float* __restrict__ bias,
    float* __restrict__ out, int N)
{
    __shared__ unsigned short hA[64][136];   // +8 pad
    __shared__ unsigned short wb[16384];
    int tid = threadIdx.x;
    int row0 = blockIdx.x * 64;

    // stage WB -> LDS, contiguous uint4 copies
    {
        const uint4* s4 = (const uint4*)WB;
        uint4* d4 = (uint4*)wb;
#pragma unroll
        for (int i = 0; i < 8; ++i)
            d4[tid + i * 256] = s4[tid + i * 256];
    }
    // stage h rows (4 threads per row, 32 bf16 each)
    {
        int r = tid >> 2, seg = tid & 3;
        int n = row0 + r;
        if (n < N) {
            const uint4* hrow = (const uint4*)(hbuf + n * D + seg * 32);
            uint4* dh = (uint4*)&hA[r][seg * 32];
#pragma unroll
            for (int i = 0; i < 4; ++i) dh[i] = hrow[i];
        }
    }
    __syncthreads();

    int wv = tid >> 6, lane = tid & 63;
    int quad = lane >> 4, l15 = lane & 15;

    short8 a[4];
#pragma unroll
    for (int ks = 0; ks < 4; ++ks)
        a[ks] = *(const short8*)&hA[wv * 16 + l15][ks * 32 + quad * 8];

    int orow = row0 + wv * 16 + quad * 4;
#pragma unroll
    for (int n = 0; n < 8; ++n) {
        f32x4 acc = {0.0f, 0.0f, 0.0f, 0.0f};
#pragma unroll
        for (int ks = 0; ks < 4; ++ks) {
            short8 bfr = *(const short8*)&wb[((n * 4 + ks) * 64 + lane) * 8];
            acc = __builtin_amdgcn_mfma_f32_16x16x32_bf16(a[ks], bfr, acc, 0, 0, 0);
        }
        float bv = bias[n * 16 + l15];
        int col = n * 16 + l15;
#pragma unroll
        for (int rg = 0; rg < 4; ++rg) {
            int row = orow + rg;
            if (row < N) out[row * D + col] = acc[rg] + bv;
        }
    }
}

extern "C" void kernel_launch(void* const* d_in, const int* in_sizes, int n_in,
                              void* d_out, int out_size, void* d_ws, size_t ws_size,
                              hipStream_t stream)
{
    const float* nfeat = (const float*)d_in[0];
    const int*   src   = (const int*)  d_in[1];
    const int*   dst   = (const int*)  d_in[2];
    const int*   eidx  = (const int*)  d_in[3];
    const float* emb   = (const float*)d_in[4];
    const float* Wm    = (const float*)d_in[5];
    const float* bias  = (const float*)d_in[6];
    float* out = (float*)d_out;

    int N = in_sizes[0] / D;   // 50000
    int E = in_sizes[1];       // 600000

    // ws: count[N] | cursor[N] | offset[N] | packed[E] | T[512*128 f32]
    //     | WB[16384 u16] | hbuf[N*128 u16]   (~16.1 MB, all 16B-aligned)
    int* count  = (int*)d_ws;
    int* cursor = count + N;
    int* offset = cursor + N;
    unsigned* packed = (unsigned*)(offset + N);
    float* T = (float*)(packed + E);
    unsigned short* WB = (unsigned short*)(T + 512 * 128);
    unsigned short* hbuf = WB + 16384;

    hipMemsetAsync(count, 0, (size_t)N * sizeof(int), stream);

    int eb = (E + 255) / 256;
    hist_kernel<<<eb, 256, 0, stream>>>(dst, count, E);
    prep_kernel<<<81, 1024, 0, stream>>>(count, offset, cursor, emb, T, Wm, WB, N);
    scatter_kernel<<<eb, 256, 0, stream>>>(src, dst, eidx, cursor, packed, E);
    gather_kernel<<<(N * 64 + 255) / 256, 256, 0, stream>>>(
        nfeat, packed, offset, count, T, hbuf, N);
    proj_kernel<<<(N + 63) / 64, 256, 0, stream>>>(hbuf, WB, bias, out, N);
}

// Round 5
// 209.632 us; speedup vs baseline: 1.4962x; 1.4962x over previous
//
#include <hip/hip_runtime.h>

#define D  128
#define NF 3
#define V  8

typedef __attribute__((ext_vector_type(8))) short short8;
typedef __attribute__((ext_vector_type(4))) float f32x4;

__device__ inline unsigned short f2bf(float x) {
    unsigned u = __builtin_bit_cast(unsigned, x);
    return (unsigned short)((u + 0x7FFFu + ((u >> 16) & 1u)) >> 16);   // RNE
}
__device__ inline float bflo(unsigned u) {
    return __builtin_bit_cast(float, u << 16);
}
__device__ inline float bfhi(unsigned u) {
    return __builtin_bit_cast(float, u & 0xFFFF0000u);
}

// ---------------- build stage ----------------

__global__ __launch_bounds__(256) void hist_kernel(
    const int* __restrict__ dst, int* __restrict__ count, int E)
{
    int t = blockIdx.x * 256 + threadIdx.x;
    if (t < E) atomicAdd(&count[dst[t]], 1);
}

// per-block sums of count[] (196 blocks)
__global__ __launch_bounds__(256) void bsum_kernel(
    const int* __restrict__ count, int* __restrict__ bsum, int N)
{
    int i = blockIdx.x * 256 + threadIdx.x;
    int v = (i < N) ? count[i] : 0;
#pragma unroll
    for (int d = 32; d > 0; d >>= 1) v += __shfl_down(v, d);
    __shared__ int ws[4];
    int lane = threadIdx.x & 63, wv = threadIdx.x >> 6;
    if (lane == 0) ws[wv] = v;
    __syncthreads();
    if (threadIdx.x == 0)
        bsum[blockIdx.x] = ws[0] + ws[1] + ws[2] + ws[3];
}

// Mixed-role: block 0 = scan of 196 block sums -> bex;
// blocks 1..256   = combined edge-embedding table Tb[512][128] (bf16);
// blocks 257..320 = W -> B-fragment-order bf16 WB[16384];
// blocks 321..6570 = nfeat fp32 -> bf16 (4 elems/thread).
__global__ __launch_bounds__(256) void mix_kernel(
    const int* __restrict__ bsum, int* __restrict__ bex, int nb,
    const float* __restrict__ emb, unsigned short* __restrict__ Tb,
    const float* __restrict__ Wm, unsigned short* __restrict__ WB,
    const float* __restrict__ nfeat, unsigned* __restrict__ nfb32, int N)
{
    int b = blockIdx.x;
    int t = threadIdx.x;
    if (b == 0) {
        int v = (t < nb) ? bsum[t] : 0;
        int lane = t & 63, wv = t >> 6;
        int inc = v;
#pragma unroll
        for (int d = 1; d < 64; d <<= 1) {
            int u = __shfl_up(inc, d);
            if (lane >= d) inc += u;
        }
        __shared__ int ws[4];
        if (lane == 63) ws[wv] = inc;
        __syncthreads();
        int base = 0;
        for (int w = 0; w < wv; ++w) base += ws[w];
        if (t < nb) bex[t] = base + inc - v;
    } else if (b <= 256) {
        int tid = (b - 1) * 256 + t;          // 0..65535
        int cmb = tid >> 7, c = tid & 127;
        float s = emb[(cmb & 7) * D + c]
                + emb[(V + ((cmb >> 3) & 7)) * D + c]
                + emb[(2 * V + (cmb >> 6)) * D + c];
        Tb[tid] = f2bf(s);
    } else if (b <= 320) {
        // WB[((n*4+ks)*64 + lane)*8 + j] = bf16(W[ks*32+(lane>>4)*8+j][n*16+(lane&15)])
        int tid = (b - 257) * 256 + t;        // 0..16383
        int j = tid & 7, lane = (tid >> 3) & 63, ks = (tid >> 9) & 3, n = tid >> 11;
        int k = ks * 32 + ((lane >> 4) << 3) + j;
        int c = n * 16 + (lane & 15);
        WB[tid] = f2bf(Wm[k * D + c]);
    } else {
        int tid = (b - 321) * 256 + t;        // 0..1599999, 4 floats each
        float4 v = ((const float4*)nfeat)[tid];
        nfb32[tid * 2 + 0] = (unsigned)f2bf(v.x) | ((unsigned)f2bf(v.y) << 16);
        nfb32[tid * 2 + 1] = (unsigned)f2bf(v.z) | ((unsigned)f2bf(v.w) << 16);
    }
}

// per-block exclusive scan of count + block prefix -> offset & cursor
__global__ __launch_bounds__(256) void offsets_kernel(
    const int* __restrict__ count, const int* __restrict__ bex,
    int* __restrict__ offset, int* __restrict__ cursor, int N)
{
    int i = blockIdx.x * 256 + threadIdx.x;
    int c = (i < N) ? count[i] : 0;
    int lane = threadIdx.x & 63, wv = threadIdx.x >> 6;
    int inc = c;
#pragma unroll
    for (int d = 1; d < 64; d <<= 1) {
        int u = __shfl_up(inc, d);
        if (lane >= d) inc += u;
    }
    __shared__ int ws[4];
    if (lane == 63) ws[wv] = inc;
    __syncthreads();
    int base = bex[blockIdx.x];
    for (int w = 0; w < wv; ++w) base += ws[w];
    if (i < N) {
        int ex = base + inc - c;
        offset[i] = ex;
        cursor[i] = ex;
    }
}

// scatter packed (src | combined_emb_idx<<16) into dst-sorted order
__global__ __launch_bounds__(256) void scatter_kernel(
    const int* __restrict__ src, const int* __restrict__ dst,
    const int* __restrict__ eidx, int* __restrict__ cursor,
    unsigned* __restrict__ packed, int E)
{
    int t = blockIdx.x * 256 + threadIdx.x;
    if (t < E) {
        int i0 = eidx[t * NF + 0];
        int i1 = eidx[t * NF + 1];
        int i2 = eidx[t * NF + 2];
        unsigned ci = (unsigned)(i0 + (i1 << 3) + (i2 << 6));
        int pos = atomicAdd(&cursor[dst[t]], 1);
        packed[pos] = (unsigned)src[t] | (ci << 16);
    }
}

// ---------------- gather: one wave per node (bf16 operands) ----------------
// Writes bf16 h row n into upper 256 B of out row n (out_u32[n*128+64+lane]).

__global__ __launch_bounds__(256) void gather_kernel(
    const float* __restrict__ nfeat,
    const unsigned* __restrict__ nfb32,
    const unsigned* __restrict__ Tb32,
    const unsigned* __restrict__ packed,
    const int* __restrict__ offset,
    const int* __restrict__ count,
    unsigned* __restrict__ out_u32,
    int N)
{
    int wid = (blockIdx.x * 256 + threadIdx.x) >> 6;
    int lane = threadIdx.x & 63;
    if (wid >= N) return;

    int off = offset[wid];
    int cnt = count[wid];
    float2 acc = ((const float2*)nfeat)[wid * 64 + lane];   // self term fp32

    for (int base = 0; base < cnt; base += 64) {
        int m = min(64, cnt - base);
        unsigned rec = (lane < m) ? packed[off + base + lane] : 0u;
        int j = 0;
        for (; j + 4 <= m; j += 4) {
            unsigned u0 = __shfl((int)rec, j);
            unsigned u1 = __shfl((int)rec, j + 1);
            unsigned u2 = __shfl((int)rec, j + 2);
            unsigned u3 = __shfl((int)rec, j + 3);
            unsigned a0 = nfb32[(u0 & 0xFFFFu) * 64 + lane];
            unsigned t0 = Tb32[(u0 >> 16) * 64 + lane];
            unsigned a1 = nfb32[(u1 & 0xFFFFu) * 64 + lane];
            unsigned t1 = Tb32[(u1 >> 16) * 64 + lane];
            unsigned a2 = nfb32[(u2 & 0xFFFFu) * 64 + lane];
            unsigned t2 = Tb32[(u2 >> 16) * 64 + lane];
            unsigned a3 = nfb32[(u3 & 0xFFFFu) * 64 + lane];
            unsigned t3 = Tb32[(u3 >> 16) * 64 + lane];
            acc.x += (bflo(a0) + bflo(t0)) + (bflo(a1) + bflo(t1))
                   + (bflo(a2) + bflo(t2)) + (bflo(a3) + bflo(t3));
            acc.y += (bfhi(a0) + bfhi(t0)) + (bfhi(a1) + bfhi(t1))
                   + (bfhi(a2) + bfhi(t2)) + (bfhi(a3) + bfhi(t3));
        }
        for (; j < m; ++j) {
            unsigned u = __shfl((int)rec, j);
            unsigned a = nfb32[(u & 0xFFFFu) * 64 + lane];
            unsigned tt = Tb32[(u >> 16) * 64 + lane];
            acc.x += bflo(a) + bflo(tt);
            acc.y += bfhi(a) + bfhi(tt);
        }
    }

    float inv = 1.0f / (float)(cnt + 1);
    acc.x *= inv; acc.y *= inv;
    out_u32[wid * 128 + 64 + lane] =
        (unsigned)f2bf(acc.x) | ((unsigned)f2bf(acc.y) << 16);
}

// ---------------- projection via MFMA: out = h @ W + b ----------------
// h rows live in upper halves of out rows; read pre-sync, write full rows post.

__global__ __launch_bounds__(256) void proj_kernel(
    const unsigned short* __restrict__ WB,
    const float* __restrict__ bias,
    float* __restrict__ out, int N)
{
    __shared__ unsigned short hA[64][136];   // +8 pad
    __shared__ unsigned short wb[16384];
    int tid = threadIdx.x;
    int row0 = blockIdx.x * 64;
    unsigned* out_u32 = (unsigned*)out;

    {
        const uint4* s4 = (const uint4*)WB;
        uint4* d4 = (uint4*)wb;
#pragma unroll
        for (int i = 0; i < 8; ++i)
            d4[tid + i * 256] = s4[tid + i * 256];
    }
    {
        int r = tid >> 2, seg = tid & 3;
        int n = row0 + r;
        if (n < N) {
            const uint4* hrow = (const uint4*)(out_u32 + n * 128 + 64 + seg * 16);
            uint4* dh = (uint4*)&hA[r][seg * 32];
#pragma unroll
            for (int i = 0; i < 4; ++i) dh[i] = hrow[i];
        }
    }
    __syncthreads();

    int wv = tid >> 6, lane = tid & 63;
    int quad = lane >> 4, l15 = lane & 15;

    short8 a[4];
#pragma unroll
    for (int ks = 0; ks < 4; ++ks)
        a[ks] = *(const short8*)&hA[wv * 16 + l15][ks * 32 + quad * 8];

    int orow = row0 + wv * 16 + quad * 4;
#pragma unroll
    for (int n = 0; n < 8; ++n) {
        f32x4 acc = {0.0f, 0.0f, 0.0f, 0.0f};
#pragma unroll
        for (int ks = 0; ks < 4; ++ks) {
            short8 bfr = *(const short8*)&wb[((n * 4 + ks) * 64 + lane) * 8];
            acc = __builtin_amdgcn_mfma_f32_16x16x32_bf16(a[ks], bfr, acc, 0, 0, 0);
        }
        float bv = bias[n * 16 + l15];
        int col = n * 16 + l15;
#pragma unroll
        for (int rg = 0; rg < 4; ++rg) {
            int row = orow + rg;
            if (row < N) out[row * D + col] = acc[rg] + bv;
        }
    }
}

extern "C" void kernel_launch(void* const* d_in, const int* in_sizes, int n_in,
                              void* d_out, int out_size, void* d_ws, size_t ws_size,
                              hipStream_t stream)
{
    const float* nfeat = (const float*)d_in[0];
    const int*   src   = (const int*)  d_in[1];
    const int*   dst   = (const int*)  d_in[2];
    const int*   eidx  = (const int*)  d_in[3];
    const float* emb   = (const float*)d_in[4];
    const float* Wm    = (const float*)d_in[5];
    const float* bias  = (const float*)d_in[6];
    float* out = (float*)d_out;

    int N = in_sizes[0] / D;   // 50000
    int E = in_sizes[1];       // 600000
    int NB = (N + 255) / 256;  // 196

    // ws: count[N] cursor[N] offset[N] bsum[256] bex[256] packed[E]
    //     Tb[65536 u16] WB[16384 u16] nfb[N*128 u16]   (~16 MB)
    int* count  = (int*)d_ws;
    int* cursor = count + N;
    int* offset = cursor + N;
    int* bsum   = offset + N;
    int* bex    = bsum + 256;
    unsigned* packed = (unsigned*)(bex + 256);
    unsigned short* Tb = (unsigned short*)(packed + E);
    unsigned short* WB = Tb + 512 * 128;
    unsigned* nfb32 = (unsigned*)(WB + 16384);

    hipMemsetAsync(count, 0, (size_t)N * sizeof(int), stream);

    int eb = (E + 255) / 256;
    hist_kernel<<<eb, 256, 0, stream>>>(dst, count, E);
    bsum_kernel<<<NB, 256, 0, stream>>>(count, bsum, N);
    mix_kernel<<<321 + (N * D / 4 + 255) / 256, 256, 0, stream>>>(
        bsum, bex, NB, emb, Tb, Wm, WB, nfeat, nfb32, N);
    offsets_kernel<<<NB, 256, 0, stream>>>(count, bex, offset, cursor, N);
    scatter_kernel<<<eb, 256, 0, stream>>>(src, dst, eidx, cursor, packed, E);
    gather_kernel<<<(N * 64 + 255) / 256, 256, 0, stream>>>(
        nfeat, nfb32, (const unsigned*)Tb, packed, offset, count,
        (unsigned*)out, N);
    proj_kernel<<<(N + 63) / 64, 256, 0, stream>>>(WB, bias, out, N);
}

// Round 6
// 206.889 us; speedup vs baseline: 1.5160x; 1.0133x over previous
//
#include <hip/hip_runtime.h>

#define D  128
#define NF 3
#define V  8

typedef __attribute__((ext_vector_type(8))) short short8;
typedef __attribute__((ext_vector_type(4))) float f32x4;

__device__ inline unsigned short f2bf(float x) {
    unsigned u = __builtin_bit_cast(unsigned, x);
    return (unsigned short)((u + 0x7FFFu + ((u >> 16) & 1u)) >> 16);   // RNE
}
__device__ inline float bflo(unsigned u) {
    return __builtin_bit_cast(float, u << 16);
}
__device__ inline float bfhi(unsigned u) {
    return __builtin_bit_cast(float, u & 0xFFFF0000u);
}

// ---------------- build: hist + pack + tables + bf16 convert ----------------
// roles by blockIdx: [0,eb) hist atomics; [eb,2eb) edge-record pack;
// [2eb,2eb+256) combined emb table Tb; [.., +64) W->B-frag WB;
// rest: nfeat fp32 -> bf16.

__global__ __launch_bounds__(256) void build_kernel(
    const int* __restrict__ src, const int* __restrict__ dst,
    const int* __restrict__ eidx, const float* __restrict__ emb,
    const float* __restrict__ Wm, const float* __restrict__ nfeat,
    int* __restrict__ count, unsigned* __restrict__ pkd,
    unsigned short* __restrict__ Tb, unsigned short* __restrict__ WB,
    unsigned* __restrict__ nfb32, int E, int eb)
{
    int b = blockIdx.x, t = threadIdx.x;
    if (b < eb) {
        int e = b * 256 + t;
        if (e < E) atomicAdd(&count[dst[e]], 1);
    } else if (b < 2 * eb) {
        int e = (b - eb) * 256 + t;
        if (e < E) {
            int i0 = eidx[e * NF + 0];
            int i1 = eidx[e * NF + 1];
            int i2 = eidx[e * NF + 2];
            pkd[e] = (unsigned)src[e]
                   | ((unsigned)(i0 + (i1 << 3) + (i2 << 6)) << 16);
        }
    } else if (b < 2 * eb + 256) {
        int tid = (b - 2 * eb) * 256 + t;          // 0..65535
        int cmb = tid >> 7, c = tid & 127;
        float s = emb[(cmb & 7) * D + c]
                + emb[(V + ((cmb >> 3) & 7)) * D + c]
                + emb[(2 * V + (cmb >> 6)) * D + c];
        Tb[tid] = f2bf(s);
    } else if (b < 2 * eb + 320) {
        // WB[((n*4+ks)*64+lane)*8+j] = bf16(W[ks*32+(lane>>4)*8+j][n*16+(lane&15)])
        int tid = (b - (2 * eb + 256)) * 256 + t;  // 0..16383
        int j = tid & 7, lane = (tid >> 3) & 63, ks = (tid >> 9) & 3, n = tid >> 11;
        int k = ks * 32 + ((lane >> 4) << 3) + j;
        int c = n * 16 + (lane & 15);
        WB[tid] = f2bf(Wm[k * D + c]);
    } else {
        int tid = (b - (2 * eb + 320)) * 256 + t;  // 4 floats each
        float4 v = ((const float4*)nfeat)[tid];
        nfb32[tid * 2 + 0] = (unsigned)f2bf(v.x) | ((unsigned)f2bf(v.y) << 16);
        nfb32[tid * 2 + 1] = (unsigned)f2bf(v.z) | ((unsigned)f2bf(v.w) << 16);
    }
}

// ---------------- single-pass scan (decoupled lookback) ----------------
// desc[b]: (sum<<2) | state; state 0=invalid, 1=aggregate, 2=inclusive prefix.

__global__ __launch_bounds__(256) void scan_kernel(
    const int* __restrict__ count, int* __restrict__ offset,
    int* __restrict__ cursor, unsigned* __restrict__ desc, int N)
{
    int b = blockIdx.x, t = threadIdx.x;
    int i = b * 256 + t;
    int c = (i < N) ? count[i] : 0;
    int lane = t & 63, wv = t >> 6;
    int inc = c;
#pragma unroll
    for (int d = 1; d < 64; d <<= 1) {
        int u = __shfl_up(inc, d);
        if (lane >= d) inc += u;
    }
    __shared__ int ws4[4];
    __shared__ int sprefix;
    if (lane == 63) ws4[wv] = inc;
    __syncthreads();
    int total = ws4[0] + ws4[1] + ws4[2] + ws4[3];
    int base = 0;
    for (int w = 0; w < wv; ++w) base += ws4[w];

    if (t == 0) {
        if (b == 0) {
            atomicExch(&desc[0], ((unsigned)total << 2) | 2u);
            sprefix = 0;
        } else {
            atomicExch(&desc[b], ((unsigned)total << 2) | 1u);   // aggregate first
        }
    }
    if (b > 0 && wv == 0) {
        int ex = 0;
        int j = b - 1;
        for (;;) {
            int idx = j - lane;
            unsigned v = 0;
            if (idx >= 0) {
                do { v = atomicAdd(&desc[idx], 0u); } while ((v & 3u) == 0u);
            }
            unsigned long long pm = __ballot(idx >= 0 && (v & 3u) == 2u);
            int contrib;
            if (pm) {
                int fl = (int)(__ffsll((unsigned long long)pm) - 1);
                contrib = (lane <= fl) ? (int)(v >> 2) : 0;
            } else {
                contrib = (idx >= 0) ? (int)(v >> 2) : 0;
            }
#pragma unroll
            for (int d = 32; d > 0; d >>= 1) contrib += __shfl_down(contrib, d);
            if (lane == 0) ex += contrib;
            if (pm) break;
            j -= 64;
        }
        if (lane == 0) {
            atomicExch(&desc[b], ((unsigned)(ex + total) << 2) | 2u);
            sprefix = ex;
        }
    }
    __syncthreads();
    if (i < N) {
        int exv = sprefix + base + inc - c;
        offset[i] = exv;
        cursor[i] = exv;
    }
}

// ---------------- scatter packed records into dst-sorted order --------------

__global__ __launch_bounds__(256) void scatter_kernel(
    const int* __restrict__ dst, const unsigned* __restrict__ pkd,
    int* __restrict__ cursor, unsigned* __restrict__ packed, int E)
{
    int e = blockIdx.x * 256 + threadIdx.x;
    if (e < E) {
        int pos = atomicAdd(&cursor[dst[e]], 1);
        packed[pos] = pkd[e];
    }
}

// ---------------- fused gather + MFMA projection ----------------
// Block = 16 nodes, 4 waves. Wave w gathers nodes row0+w*4..+3 into LDS h-tile,
// then computes cols [w*32, w*32+32) of the 16x128 output via MFMA.

__global__ __launch_bounds__(256) void fused_gp(
    const float* __restrict__ nfeat,
    const unsigned* __restrict__ nfb32,
    const unsigned* __restrict__ Tb32,
    const unsigned* __restrict__ packed,
    const int* __restrict__ offset,
    const int* __restrict__ count,
    const unsigned short* __restrict__ WB,
    const float* __restrict__ bias,
    float* __restrict__ out, int N)
{
    __shared__ unsigned short hA[16][136];   // +8 pad
    int t = threadIdx.x, w = t >> 6, lane = t & 63;
    int quad = lane >> 4, l15 = lane & 15;
    int row0 = blockIdx.x * 16;

    // Prefetch this wave's B fragments (independent of gather -> overlaps)
    short8 bf[2][4];
#pragma unroll
    for (int ni = 0; ni < 2; ++ni)
#pragma unroll
        for (int ks = 0; ks < 4; ++ks) {
            int n = w * 2 + ni;
            bf[ni][ks] = *(const short8*)&WB[((n * 4 + ks) * 64 + lane) * 8];
        }

    // Phase 1: gather
    for (int i = 0; i < 4; ++i) {
        int n = row0 + w * 4 + i;
        if (n >= N) break;
        int off = offset[n], cnt = count[n];
        float2 acc = ((const float2*)nfeat)[n * 64 + lane];   // self term fp32
        for (int base = 0; base < cnt; base += 64) {
            int m = min(64, cnt - base);
            unsigned rec = (lane < m) ? packed[off + base + lane] : 0u;
            int j = 0;
            for (; j + 4 <= m; j += 4) {
                unsigned u0 = __shfl((int)rec, j);
                unsigned u1 = __shfl((int)rec, j + 1);
                unsigned u2 = __shfl((int)rec, j + 2);
                unsigned u3 = __shfl((int)rec, j + 3);
                unsigned a0 = nfb32[(u0 & 0xFFFFu) * 64 + lane];
                unsigned t0 = Tb32[(u0 >> 16) * 64 + lane];
                unsigned a1 = nfb32[(u1 & 0xFFFFu) * 64 + lane];
                unsigned t1 = Tb32[(u1 >> 16) * 64 + lane];
                unsigned a2 = nfb32[(u2 & 0xFFFFu) * 64 + lane];
                unsigned t2 = Tb32[(u2 >> 16) * 64 + lane];
                unsigned a3 = nfb32[(u3 & 0xFFFFu) * 64 + lane];
                unsigned t3 = Tb32[(u3 >> 16) * 64 + lane];
                acc.x += (bflo(a0) + bflo(t0)) + (bflo(a1) + bflo(t1))
                       + (bflo(a2) + bflo(t2)) + (bflo(a3) + bflo(t3));
                acc.y += (bfhi(a0) + bfhi(t0)) + (bfhi(a1) + bfhi(t1))
                       + (bfhi(a2) + bfhi(t2)) + (bfhi(a3) + bfhi(t3));
            }
            for (; j < m; ++j) {
                unsigned u = __shfl((int)rec, j);
                unsigned a = nfb32[(u & 0xFFFFu) * 64 + lane];
                unsigned tt = Tb32[(u >> 16) * 64 + lane];
                acc.x += bflo(a) + bflo(tt);
                acc.y += bfhi(a) + bfhi(tt);
            }
        }
        float inv = 1.0f / (float)(cnt + 1);
        acc.x *= inv; acc.y *= inv;
        *(unsigned*)&hA[w * 4 + i][2 * lane] =
            (unsigned)f2bf(acc.x) | ((unsigned)f2bf(acc.y) << 16);
    }
    __syncthreads();

    // Phase 2: 16x128 = A(16x128) @ W(128x128) slice per wave
    short8 a[4];
#pragma unroll
    for (int ks = 0; ks < 4; ++ks)
        a[ks] = *(const short8*)&hA[l15][ks * 32 + quad * 8];

#pragma unroll
    for (int ni = 0; ni < 2; ++ni) {
        int n = w * 2 + ni;
        f32x4 acc = {0.0f, 0.0f, 0.0f, 0.0f};
#pragma unroll
        for (int ks = 0; ks < 4; ++ks)
            acc = __builtin_amdgcn_mfma_f32_16x16x32_bf16(a[ks], bf[ni][ks], acc, 0, 0, 0);
        float bv = bias[n * 16 + l15];
        int col = n * 16 + l15;
#pragma unroll
        for (int rg = 0; rg < 4; ++rg) {
            int row = row0 + quad * 4 + rg;
            if (row < N) out[row * D + col] = acc[rg] + bv;
        }
    }
}

extern "C" void kernel_launch(void* const* d_in, const int* in_sizes, int n_in,
                              void* d_out, int out_size, void* d_ws, size_t ws_size,
                              hipStream_t stream)
{
    const float* nfeat = (const float*)d_in[0];
    const int*   src   = (const int*)  d_in[1];
    const int*   dst   = (const int*)  d_in[2];
    const int*   eidx  = (const int*)  d_in[3];
    const float* emb   = (const float*)d_in[4];
    const float* Wm    = (const float*)d_in[5];
    const float* bias  = (const float*)d_in[6];
    float* out = (float*)d_out;

    int N = in_sizes[0] / D;   // 50000
    int E = in_sizes[1];       // 600000
    int eb = (E + 255) / 256;  // 2344
    int NB = (N + 255) / 256;  // 196

    // ws: count[N] | desc[256] | cursor[N] | offset[N] | pkd[E] | packed[E]
    //     | Tb[65536 u16] | WB[16384 u16] | nfb[N*128 u16]    (~18.4 MB)
    int* count = (int*)d_ws;
    unsigned* desc = (unsigned*)(count + N);
    int* cursor = (int*)(desc + 256);
    int* offset = cursor + N;
    unsigned* pkd = (unsigned*)(offset + N);
    unsigned* packed = pkd + E;
    unsigned short* Tb = (unsigned short*)(packed + E);
    unsigned short* WB = Tb + 512 * 128;
    unsigned* nfb32 = (unsigned*)(WB + 16384);

    // zero count[] and lookback descriptors in one contiguous memset
    hipMemsetAsync(count, 0, ((size_t)N + 256) * sizeof(int), stream);

    int nfb_blocks = (N * D / 4 + 255) / 256;   // 6250
    build_kernel<<<2 * eb + 320 + nfb_blocks, 256, 0, stream>>>(
        src, dst, eidx, emb, Wm, nfeat, count, pkd, Tb, WB, nfb32, E, eb);
    scan_kernel<<<NB, 256, 0, stream>>>(count, offset, cursor, desc, N);
    scatter_kernel<<<eb, 256, 0, stream>>>(dst, pkd, cursor, packed, E);
    fused_gp<<<(N + 15) / 16, 256, 0, stream>>>(
        nfeat, nfb32, (const unsigned*)Tb, packed, offset, count,
        WB, bias, out, N);
}